// Round 10
// baseline (1206.864 us; speedup 1.0000x reference)
//
#include <hip/hip_runtime.h>
#include <hip/hip_fp16.h>

#define N_NODES   100000
#define N_EDGES   3200000
#define N_FEAT    128
#define HIDDEN    16
#define N_CLASSES 10
#define N_GRAPHS  512
#define NPB       256                      // dst nodes per bucket
#define NBUCKET   391                      // ceil(N_NODES / NPB)
#define EPB       4096                     // edges per partition block
#define PBLK      ((N_EDGES + EPB - 1) / EPB)   // 782
#define PSLACK    15872                    // part stride/bucket (words); 16-aligned
#define ASTR      17                       // acc row stride (17 coprime 32)

// ---------------- partition: LDS counting sort + line-aligned flush ----------------

__global__ void cursor_init_kernel(int* __restrict__ cur) {
    int i = blockIdx.x * 256 + threadIdx.x;
    if (i < NBUCKET) cur[i] = i * PSLACK;
}

// record: src | (dst&255)<<17 ; sentinel 0xFFFFFFFF fills 64B-alignment padding
__global__ __launch_bounds__(512) void partition_kernel(const int* __restrict__ src,
                                                        const int* __restrict__ dst,
                                                        int* __restrict__ cur,
                                                        unsigned* __restrict__ part) {
    __shared__ int cnt[NBUCKET];
    __shared__ int lbase[NBUCKET];
    __shared__ int rk[NBUCKET];
    __shared__ int gbase[NBUCKET];
    __shared__ int s[512];
    __shared__ unsigned sorted[EPB];
    int tid = threadIdx.x;
    for (int i = tid; i < NBUCKET; i += 512) cnt[i] = 0;
    __syncthreads();
    int s0 = blockIdx.x * EPB;
#pragma unroll
    for (int i = 0; i < EPB / 512; ++i) {
        int e = s0 + i * 512 + tid;
        if (e < N_EDGES) atomicAdd(&cnt[dst[e] >> 8], 1);
    }
    __syncthreads();
    int v = (tid < NBUCKET) ? cnt[tid] : 0;
    s[tid] = v;
    __syncthreads();
    for (int off = 1; off < 512; off <<= 1) {
        int t = (tid >= off) ? s[tid - off] : 0;
        __syncthreads();
        s[tid] += t;
        __syncthreads();
    }
    if (tid < NBUCKET) {
        int lb = s[tid] - v;
        lbase[tid] = lb;
        rk[tid]    = lb;
        int cpad = (v + 15) & ~15;                 // 64B-aligned reservation
        gbase[tid] = cpad ? atomicAdd(&cur[tid], cpad) : 0;
    }
    __syncthreads();
    // pass 2: re-read edges (L2-hot), rank-scatter into LDS
#pragma unroll
    for (int i = 0; i < EPB / 512; ++i) {
        int e = s0 + i * 512 + tid;
        if (e < N_EDGES) {
            int d = dst[e];
            int b = d >> 8;
            int r = atomicAdd(&rk[b], 1);
            sorted[r] = (unsigned)src[e] | ((unsigned)(d & 255) << 17);
        }
    }
    __syncthreads();
    // flush: 16-lane groups, contiguous 64B-aligned fully-written lines
    int w16 = tid >> 4, l16 = tid & 15;
    for (int b = w16; b < NBUCKET; b += 32) {
        int c = cnt[b];
        if (!c) continue;
        int cpad = (c + 15) & ~15;
        int lb = lbase[b], gb = gbase[b];
        for (int j = l16; j < cpad; j += 16)
            part[gb + j] = (j < c) ? sorted[lb + j] : 0xFFFFFFFFu;
    }
}

// one block per bucket: degree count over the slack region -> dinv
__global__ __launch_bounds__(512) void deg_dinv_kernel(const unsigned* __restrict__ part,
                                                       const int* __restrict__ cur,
                                                       float* __restrict__ dinv) {
    __shared__ int ncnt[NPB];
    int b   = blockIdx.x;
    int tid = threadIdx.x;
    if (tid < NPB) ncnt[tid] = 0;
    __syncthreads();
    int base = b * PSLACK, end = cur[b];
    for (int j = base + tid; j < end; j += 512) {
        unsigned r = part[j];
        if (r != 0xFFFFFFFFu) atomicAdd(&ncnt[(r >> 17) & 255], 1);
    }
    __syncthreads();
    if (tid < NPB) {
        int v = b * NPB + tid;
        if (v < N_NODES) dinv[v] = rsqrtf((float)(ncnt[tid] + 1));  // +1 self-loop
    }
}

// ---------------- layer kernels (g, h stored fp16: row = 16 halves = 32B) ----------------

__device__ __forceinline__ void pack_store8(__half* outp, int idx, const float* o) {
    int4 w;
    __half2 q;
    q = __floats2half2_rn(o[0], o[1]); w.x = *(int*)&q;
    q = __floats2half2_rn(o[2], o[3]); w.y = *(int*)&q;
    q = __floats2half2_rn(o[4], o[5]); w.z = *(int*)&q;
    q = __floats2half2_rn(o[6], o[7]); w.w = *(int*)&q;
    ((int4*)outp)[idx] = w;
}

// g[v] = dinv[v] * (x[v] @ W1), x: [N,128] fp32, W: [128,16], g: fp16
__global__ void transform_x_kernel(const float* __restrict__ x, const float* __restrict__ W,
                                   const float* __restrict__ dinv, __half* __restrict__ g) {
    __shared__ float Wl[N_FEAT * HIDDEN];
    int tid = threadIdx.x;
    for (int i = tid; i < N_FEAT * HIDDEN; i += 256) Wl[i] = W[i];
    __syncthreads();
    int v = blockIdx.x * 256 + tid;
    if (v >= N_NODES) return;
    float acc[HIDDEN];
#pragma unroll
    for (int f = 0; f < HIDDEN; ++f) acc[f] = 0.f;
    const float4* xr = (const float4*)(x + (size_t)v * N_FEAT);
#pragma unroll 4
    for (int k4 = 0; k4 < N_FEAT / 4; ++k4) {
        float4 xv = xr[k4];
        const float* wr = &Wl[k4 * 4 * HIDDEN];
#pragma unroll
        for (int f = 0; f < HIDDEN; ++f)
            acc[f] += xv.x * wr[f] + xv.y * wr[HIDDEN + f] +
                      xv.z * wr[2 * HIDDEN + f] + xv.w * wr[3 * HIDDEN + f];
    }
    float di = dinv[v];
#pragma unroll
    for (int f = 0; f < HIDDEN; ++f) acc[f] *= di;
    pack_store8(g, v * 2,     &acc[0]);
    pack_store8(g, v * 2 + 1, &acc[8]);
}

// g[v] = dinv[v] * (h[v] @ W), h: [N,16] fp16, W: [16,16], g: fp16
__global__ void transform_h_kernel(const __half* __restrict__ h, const float* __restrict__ W,
                                   const float* __restrict__ dinv, __half* __restrict__ g) {
    __shared__ float Wl[HIDDEN * HIDDEN];
    int tid = threadIdx.x;
    if (tid < HIDDEN * HIDDEN) Wl[tid] = W[tid];
    __syncthreads();
    int v = blockIdx.x * 256 + tid;
    if (v >= N_NODES) return;
    int4 r0 = ((const int4*)h)[v * 2];
    int4 r1 = ((const int4*)h)[v * 2 + 1];
    float hv[HIDDEN];
    {
        const int rr[8] = {r0.x, r0.y, r0.z, r0.w, r1.x, r1.y, r1.z, r1.w};
#pragma unroll
        for (int q = 0; q < 8; ++q) {
            __half2 p = *(const __half2*)&rr[q];
            float2 f2 = __half22float2(p);
            hv[q * 2] = f2.x; hv[q * 2 + 1] = f2.y;
        }
    }
    float acc[HIDDEN];
#pragma unroll
    for (int f = 0; f < HIDDEN; ++f) acc[f] = 0.f;
#pragma unroll
    for (int k = 0; k < HIDDEN; ++k) {
        float hk = hv[k];
#pragma unroll
        for (int f = 0; f < HIDDEN; ++f) acc[f] += hk * Wl[k * HIDDEN + f];
    }
    float di = dinv[v];
#pragma unroll
    for (int f = 0; f < HIDDEN; ++f) acc[f] *= di;
    pack_store8(g, v * 2,     &acc[0]);
    pack_store8(g, v * 2 + 1, &acc[8]);
}

// ---------------- aggregate v5: stream part, non-returning LDS float atomics ----------------
// one block per 256-node bucket; 512 threads; acc[256][17] fp32 in LDS.
// h[v][f] = act( dinv[v] * (g[v][f] + sum_edges g[src][f]) + bias[f] )
__global__ __launch_bounds__(512) void aggregate_kernel(
        const __half* __restrict__ gin, const unsigned* __restrict__ part,
        const int* __restrict__ cur, const float* __restrict__ dinv,
        const float* __restrict__ bias, __half* __restrict__ hout, int do_relu) {
    __shared__ float acc[NPB * ASTR];      // 17408 B
    int b   = blockIdx.x;
    int tid = threadIdx.x;
    for (int i = tid; i < NPB * ASTR; i += 512) acc[i] = 0.f;
    __syncthreads();
    int base = b * PSLACK;
    int n4   = (cur[b] - base) >> 2;       // region is 16-entry aligned
    const int4* p4 = (const int4*)(part + base);
    const int4* g4 = (const int4*)gin;
    for (int i = tid; i < n4; i += 512) {
        int4 rec = p4[i];
#pragma unroll
        for (int k = 0; k < 4; ++k) {
            int ri = (k == 0) ? rec.x : (k == 1) ? rec.y : (k == 2) ? rec.z : rec.w;
            if (ri != -1) {
                unsigned r = (unsigned)ri;
                int sI = r & 0x1FFFF;
                int d  = (r >> 17) & 255;
                int4 r0 = g4[sI * 2];
                int4 r1 = g4[sI * 2 + 1];
                float* a = &acc[d * ASTR];
                float2 f;
                f = __half22float2(*(const __half2*)&r0.x); atomicAdd(&a[0],  f.x); atomicAdd(&a[1],  f.y);
                f = __half22float2(*(const __half2*)&r0.y); atomicAdd(&a[2],  f.x); atomicAdd(&a[3],  f.y);
                f = __half22float2(*(const __half2*)&r0.z); atomicAdd(&a[4],  f.x); atomicAdd(&a[5],  f.y);
                f = __half22float2(*(const __half2*)&r0.w); atomicAdd(&a[6],  f.x); atomicAdd(&a[7],  f.y);
                f = __half22float2(*(const __half2*)&r1.x); atomicAdd(&a[8],  f.x); atomicAdd(&a[9],  f.y);
                f = __half22float2(*(const __half2*)&r1.y); atomicAdd(&a[10], f.x); atomicAdd(&a[11], f.y);
                f = __half22float2(*(const __half2*)&r1.z); atomicAdd(&a[12], f.x); atomicAdd(&a[13], f.y);
                f = __half22float2(*(const __half2*)&r1.w); atomicAdd(&a[14], f.x); atomicAdd(&a[15], f.y);
            }
        }
    }
    __syncthreads();
    if (tid < NPB) {
        int v = b * NPB + tid;
        if (v < N_NODES) {
            int4 r0 = g4[v * 2];           // self-loop contribution
            int4 r1 = g4[v * 2 + 1];
            float self[16];
            {
                const int rr[8] = {r0.x, r0.y, r0.z, r0.w, r1.x, r1.y, r1.z, r1.w};
#pragma unroll
                for (int q = 0; q < 8; ++q) {
                    float2 f2 = __half22float2(*(const __half2*)&rr[q]);
                    self[q * 2] = f2.x; self[q * 2 + 1] = f2.y;
                }
            }
            float di = dinv[v];
            float o[16];
#pragma unroll
            for (int f = 0; f < HIDDEN; ++f) {
                float val = di * (acc[tid * ASTR + f] + self[f]) + bias[f];
                o[f] = do_relu ? fmaxf(val, 0.f) : val;
            }
            pack_store8(hout, v * 2,     &o[0]);
            pack_store8(hout, v * 2 + 1, &o[8]);
        }
    }
}

// ---------------- fused pooling + head (batch is sorted -> contiguous graph ranges) ----------------

__global__ void pool_head_kernel(const __half* __restrict__ h, const int* __restrict__ batch,
                                 const float* __restrict__ Wlin, const float* __restrict__ blin,
                                 float* __restrict__ out) {
    __shared__ float red[256];
    __shared__ int bounds[2];
    int g   = blockIdx.x;
    int tid = threadIdx.x;
    if (tid < 2) {
        int target = g + tid;   // lower_bound(batch, target)
        int lo = 0, hi = N_NODES;
        while (lo < hi) {
            int mid = (lo + hi) >> 1;
            if (batch[mid] < target) lo = mid + 1; else hi = mid;
        }
        bounds[tid] = lo;
    }
    __syncthreads();
    int start = bounds[0], end = bounds[1];
    int f = tid & 15, r = tid >> 4;
    float acc = 0.f;
    for (int v = start + r; v < end; v += 16)
        acc += __half2float(h[v * HIDDEN + f]);
    red[tid] = acc;
    __syncthreads();
    for (int off = 128; off >= 16; off >>= 1) {
        if (tid < off) red[tid] += red[tid + off];
        __syncthreads();
    }
    if (tid < N_CLASSES) {
        float s = blin[tid];
#pragma unroll
        for (int fe = 0; fe < HIDDEN; ++fe) s += red[fe] * Wlin[fe * N_CLASSES + tid];
        out[g * N_CLASSES + tid] = s;
    }
}

// ---------------- launch ----------------

extern "C" void kernel_launch(void* const* d_in, const int* in_sizes, int n_in,
                              void* d_out, int out_size, void* d_ws, size_t ws_size,
                              hipStream_t stream) {
    const float* x     = (const float*)d_in[0];
    const int*   ei    = (const int*)d_in[1];
    const int*   src   = ei;
    const int*   dst   = ei + N_EDGES;
    const int*   batch = (const int*)d_in[2];
    const float* W1 = (const float*)d_in[3];
    const float* b1 = (const float*)d_in[4];
    const float* W2 = (const float*)d_in[5];
    const float* b2 = (const float*)d_in[6];
    const float* W3 = (const float*)d_in[7];
    const float* b3 = (const float*)d_in[8];
    const float* Wlin = (const float*)d_in[9];
    const float* blin = (const float*)d_in[10];
    float* out = (float*)d_out;

    char* w = (char*)d_ws;
    auto alloc = [&](size_t bytes) -> char* {
        char* p = w;
        w += (bytes + 255) & ~(size_t)255;
        return p;
    };
    int*    cur    = (int*)alloc((size_t)NBUCKET * 4);
    float*  dinv   = (float*)alloc((size_t)N_NODES * 4);
    __half* g      = (__half*)alloc((size_t)N_NODES * HIDDEN * 2);
    __half* hA     = (__half*)alloc((size_t)N_NODES * HIDDEN * 2);
    __half* hB     = (__half*)alloc((size_t)N_NODES * HIDDEN * 2);
    unsigned* part = (unsigned*)alloc((size_t)NBUCKET * PSLACK * 4);  // 24.8 MB

    int nbn = (N_NODES + 255) / 256;        // 391

    cursor_init_kernel<<<(NBUCKET + 255) / 256, 256, 0, stream>>>(cur);
    partition_kernel<<<PBLK, 512, 0, stream>>>(src, dst, cur, part);
    deg_dinv_kernel<<<NBUCKET, 512, 0, stream>>>(part, cur, dinv);

    // layer 1
    transform_x_kernel<<<nbn, 256, 0, stream>>>(x, W1, dinv, g);
    aggregate_kernel<<<NBUCKET, 512, 0, stream>>>(g, part, cur, dinv, b1, hA, 1);
    // layer 2
    transform_h_kernel<<<nbn, 256, 0, stream>>>(hA, W2, dinv, g);
    aggregate_kernel<<<NBUCKET, 512, 0, stream>>>(g, part, cur, dinv, b2, hB, 1);
    // layer 3 (no relu)
    transform_h_kernel<<<nbn, 256, 0, stream>>>(hB, W3, dinv, g);
    aggregate_kernel<<<NBUCKET, 512, 0, stream>>>(g, part, cur, dinv, b3, hA, 0);

    pool_head_kernel<<<N_GRAPHS, 256, 0, stream>>>(hA, batch, Wlin, blin, out);
}

// Round 11
// 280.892 us; speedup vs baseline: 4.2965x; 4.2965x over previous
//
#include <hip/hip_runtime.h>
#include <hip/hip_fp16.h>

#define N_NODES   100000
#define N_EDGES   3200000
#define N_FEAT    128
#define HIDDEN    16
#define N_CLASSES 10
#define N_GRAPHS  512
#define NPB       256                      // dst nodes per bucket
#define NBUCKET   391                      // ceil(N_NODES / NPB)
#define EPB       4096                     // edges per partition block
#define PBLK      ((N_EDGES + EPB - 1) / EPB)   // 782
#define PSLACK    15872                    // part stride/bucket (words); 16-aligned
#define CSLACK    10240                    // csr stride/bucket: 8184 + 768 align-pad + margin

// ---------------- partition: LDS counting sort + line-aligned flush ----------------

__global__ void cursor_init_kernel(int* __restrict__ cur) {
    int i = blockIdx.x * 256 + threadIdx.x;
    if (i < NBUCKET) cur[i] = i * PSLACK;
}

// record: src | (dst&255)<<17 ; sentinel 0xFFFFFFFF fills 64B-alignment padding
__global__ __launch_bounds__(512) void partition_kernel(const int* __restrict__ src,
                                                        const int* __restrict__ dst,
                                                        int* __restrict__ cur,
                                                        unsigned* __restrict__ part) {
    __shared__ int cnt[NBUCKET];
    __shared__ int lbase[NBUCKET];
    __shared__ int rk[NBUCKET];
    __shared__ int gbase[NBUCKET];
    __shared__ int s[512];
    __shared__ unsigned sorted[EPB];
    int tid = threadIdx.x;
    for (int i = tid; i < NBUCKET; i += 512) cnt[i] = 0;
    __syncthreads();
    int s0 = blockIdx.x * EPB;
#pragma unroll
    for (int i = 0; i < EPB / 512; ++i) {
        int e = s0 + i * 512 + tid;
        if (e < N_EDGES) atomicAdd(&cnt[dst[e] >> 8], 1);
    }
    __syncthreads();
    int v = (tid < NBUCKET) ? cnt[tid] : 0;
    s[tid] = v;
    __syncthreads();
    for (int off = 1; off < 512; off <<= 1) {
        int t = (tid >= off) ? s[tid - off] : 0;
        __syncthreads();
        s[tid] += t;
        __syncthreads();
    }
    if (tid < NBUCKET) {
        int lb = s[tid] - v;
        lbase[tid] = lb;
        rk[tid]    = lb;
        int cpad = (v + 15) & ~15;                 // 64B-aligned reservation
        gbase[tid] = cpad ? atomicAdd(&cur[tid], cpad) : 0;
    }
    __syncthreads();
    // pass 2: re-read edges (L2-hot), rank-scatter into LDS
#pragma unroll
    for (int i = 0; i < EPB / 512; ++i) {
        int e = s0 + i * 512 + tid;
        if (e < N_EDGES) {
            int d = dst[e];
            int b = d >> 8;
            int r = atomicAdd(&rk[b], 1);
            sorted[r] = (unsigned)src[e] | ((unsigned)(d & 255) << 17);
        }
    }
    __syncthreads();
    // flush: 16-lane groups, contiguous 64B-aligned fully-written lines
    int w16 = tid >> 4, l16 = tid & 15;
    for (int b = w16; b < NBUCKET; b += 32) {
        int c = cnt[b];
        if (!c) continue;
        int cpad = (c + 15) & ~15;
        int lb = lbase[b], gb = gbase[b];
        for (int j = l16; j < cpad; j += 16)
            part[gb + j] = (j < c) ? sorted[lb + j] : 0xFFFFFFFFu;
    }
}

// one block per bucket (512 thr): count/scan/fill; each node's csr row start 4-aligned
__global__ __launch_bounds__(512) void build_csr_kernel(const unsigned* __restrict__ part,
                                                        const int* __restrict__ cur,
                                                        int* __restrict__ rp_beg, int* __restrict__ rp_end,
                                                        float* __restrict__ dinv, int* __restrict__ csr) {
    __shared__ int ncnt[256];
    __shared__ int s[512];
    int b   = blockIdx.x;
    int tid = threadIdx.x;
    int beg = b * PSLACK, end = cur[b];
    if (tid < 256) ncnt[tid] = 0;
    __syncthreads();
    for (int j = beg + tid; j < end; j += 512) {
        unsigned r = part[j];
        if (r != 0xFFFFFFFFu) atomicAdd(&ncnt[(r >> 17) & 255], 1);
    }
    __syncthreads();
    int deg   = (tid < 256) ? ncnt[tid] : 0;
    int alloc = (deg + 3) & ~3;            // 4-aligned row allocation
    s[tid] = alloc;
    __syncthreads();
    for (int off = 1; off < 512; off <<= 1) {
        int t = (tid >= off) ? s[tid - off] : 0;
        __syncthreads();
        s[tid] += t;
        __syncthreads();
    }
    int excl = s[tid] - alloc;
    int cbeg = b * CSLACK;
    if (tid < 256) {
        int node = b * 256 + tid;
        if (node < N_NODES) {
            rp_beg[node] = cbeg + excl;
            rp_end[node] = cbeg + excl + deg;
            dinv[node]   = rsqrtf((float)(deg + 1));  // +1 self-loop
        }
    }
    __syncthreads();
    if (tid < 256) ncnt[tid] = cbeg + excl;   // absolute fill cursor
    __syncthreads();
    for (int j = beg + tid; j < end; j += 512) {
        unsigned r = part[j];
        if (r != 0xFFFFFFFFu) {
            int vv = (r >> 17) & 255;
            int slot = atomicAdd(&ncnt[vv], 1);
            csr[slot] = (int)(r & 0x1FFFFu);
        }
    }
}

// ---------------- layer kernels (g, h stored fp16: row = 16 halves = 32B) ----------------

__device__ __forceinline__ void pack_store8(__half* outp, int idx, const float* o) {
    int4 w;
    __half2 q;
    q = __floats2half2_rn(o[0], o[1]); w.x = *(int*)&q;
    q = __floats2half2_rn(o[2], o[3]); w.y = *(int*)&q;
    q = __floats2half2_rn(o[4], o[5]); w.z = *(int*)&q;
    q = __floats2half2_rn(o[6], o[7]); w.w = *(int*)&q;
    ((int4*)outp)[idx] = w;
}

// g[v] = dinv[v] * (x[v] @ W1), x: [N,128] fp32, W: [128,16], g: fp16
__global__ void transform_x_kernel(const float* __restrict__ x, const float* __restrict__ W,
                                   const float* __restrict__ dinv, __half* __restrict__ g) {
    __shared__ float Wl[N_FEAT * HIDDEN];
    int tid = threadIdx.x;
    for (int i = tid; i < N_FEAT * HIDDEN; i += 256) Wl[i] = W[i];
    __syncthreads();
    int v = blockIdx.x * 256 + tid;
    if (v >= N_NODES) return;
    float acc[HIDDEN];
#pragma unroll
    for (int f = 0; f < HIDDEN; ++f) acc[f] = 0.f;
    const float4* xr = (const float4*)(x + (size_t)v * N_FEAT);
#pragma unroll 4
    for (int k4 = 0; k4 < N_FEAT / 4; ++k4) {
        float4 xv = xr[k4];
        const float* wr = &Wl[k4 * 4 * HIDDEN];
#pragma unroll
        for (int f = 0; f < HIDDEN; ++f)
            acc[f] += xv.x * wr[f] + xv.y * wr[HIDDEN + f] +
                      xv.z * wr[2 * HIDDEN + f] + xv.w * wr[3 * HIDDEN + f];
    }
    float di = dinv[v];
#pragma unroll
    for (int f = 0; f < HIDDEN; ++f) acc[f] *= di;
    pack_store8(g, v * 2,     &acc[0]);
    pack_store8(g, v * 2 + 1, &acc[8]);
}

// g[v] = dinv[v] * (h[v] @ W), h: [N,16] fp16, W: [16,16], g: fp16
__global__ void transform_h_kernel(const __half* __restrict__ h, const float* __restrict__ W,
                                   const float* __restrict__ dinv, __half* __restrict__ g) {
    __shared__ float Wl[HIDDEN * HIDDEN];
    int tid = threadIdx.x;
    if (tid < HIDDEN * HIDDEN) Wl[tid] = W[tid];
    __syncthreads();
    int v = blockIdx.x * 256 + tid;
    if (v >= N_NODES) return;
    int4 r0 = ((const int4*)h)[v * 2];
    int4 r1 = ((const int4*)h)[v * 2 + 1];
    float hv[HIDDEN];
    {
        const int rr[8] = {r0.x, r0.y, r0.z, r0.w, r1.x, r1.y, r1.z, r1.w};
#pragma unroll
        for (int q = 0; q < 8; ++q) {
            __half2 p = *(const __half2*)&rr[q];
            float2 f2 = __half22float2(p);
            hv[q * 2] = f2.x; hv[q * 2 + 1] = f2.y;
        }
    }
    float acc[HIDDEN];
#pragma unroll
    for (int f = 0; f < HIDDEN; ++f) acc[f] = 0.f;
#pragma unroll
    for (int k = 0; k < HIDDEN; ++k) {
        float hk = hv[k];
#pragma unroll
        for (int f = 0; f < HIDDEN; ++f) acc[f] += hk * Wl[k * HIDDEN + f];
    }
    float di = dinv[v];
#pragma unroll
    for (int f = 0; f < HIDDEN; ++f) acc[f] *= di;
    pack_store8(g, v * 2,     &acc[0]);
    pack_store8(g, v * 2 + 1, &acc[8]);
}

// ---------------- aggregate v6: 1 lane/edge, int4 csr loads, 16-chunk butterfly ----------------
// lane = c*4 + vl  (c: chunk 0..15, vl: node 0..3); wave handles 4 nodes.
// lane c loads csr entries [64k+4c, 64k+4c+4) via one int4, gathers both 16B halves per edge.
__global__ __launch_bounds__(256) void aggregate_kernel(
        const __half* __restrict__ g, const int* __restrict__ rp_beg,
        const int* __restrict__ rp_end, const int* __restrict__ csr,
        const float* __restrict__ dinv, const float* __restrict__ bias,
        __half* __restrict__ hout, int do_relu) {
    int tid  = threadIdx.x;
    int wave = tid >> 6;
    int l    = tid & 63;
    int vl = l & 3;
    int c  = l >> 2;
    int v = blockIdx.x * 16 + wave * 4 + vl;   // 6250*16 == 100000 exactly
    int beg = rp_beg[v];                        // 4-aligned
    int deg = rp_end[v] - beg;
    const int4* g4 = (const int4*)g;
    float a[16];
#pragma unroll
    for (int i = 0; i < 16; ++i) a[i] = 0.f;
    for (int j = 4 * c; j < deg; j += 64) {
        int4 e4 = *(const int4*)(csr + beg + j);   // row start 4-aligned -> aligned int4
#pragma unroll
        for (int k = 0; k < 4; ++k) {
            if (j + k < deg) {
                int sI = (k == 0) ? e4.x : (k == 1) ? e4.y : (k == 2) ? e4.z : e4.w;
                int4 r0 = g4[sI * 2];
                int4 r1 = g4[sI * 2 + 1];
                float2 f;
                f = __half22float2(*(const __half2*)&r0.x); a[0]  += f.x; a[1]  += f.y;
                f = __half22float2(*(const __half2*)&r0.y); a[2]  += f.x; a[3]  += f.y;
                f = __half22float2(*(const __half2*)&r0.z); a[4]  += f.x; a[5]  += f.y;
                f = __half22float2(*(const __half2*)&r0.w); a[6]  += f.x; a[7]  += f.y;
                f = __half22float2(*(const __half2*)&r1.x); a[8]  += f.x; a[9]  += f.y;
                f = __half22float2(*(const __half2*)&r1.y); a[10] += f.x; a[11] += f.y;
                f = __half22float2(*(const __half2*)&r1.z); a[12] += f.x; a[13] += f.y;
                f = __half22float2(*(const __half2*)&r1.w); a[14] += f.x; a[15] += f.y;
            }
        }
    }
    // butterfly over chunk bits (lane bits 2..5): xor 4, 8, 16, 32
#pragma unroll
    for (int off = 4; off <= 32; off <<= 1) {
#pragma unroll
        for (int i = 0; i < 16; ++i) a[i] += __shfl_xor(a[i], off);
    }
    if (c == 0) {
        int4 r0 = g4[v * 2];       // self-loop contribution
        int4 r1 = g4[v * 2 + 1];
        float self[16];
        {
            const int rr[8] = {r0.x, r0.y, r0.z, r0.w, r1.x, r1.y, r1.z, r1.w};
#pragma unroll
            for (int q = 0; q < 8; ++q) {
                float2 f2 = __half22float2(*(const __half2*)&rr[q]);
                self[q * 2] = f2.x; self[q * 2 + 1] = f2.y;
            }
        }
        float di = dinv[v];
        float o[16];
#pragma unroll
        for (int f = 0; f < HIDDEN; ++f) {
            float val = di * (a[f] + self[f]) + bias[f];
            o[f] = do_relu ? fmaxf(val, 0.f) : val;
        }
        pack_store8(hout, v * 2,     &o[0]);
        pack_store8(hout, v * 2 + 1, &o[8]);
    }
}

// ---------------- fused pooling + head (batch is sorted -> contiguous graph ranges) ----------------

__global__ void pool_head_kernel(const __half* __restrict__ h, const int* __restrict__ batch,
                                 const float* __restrict__ Wlin, const float* __restrict__ blin,
                                 float* __restrict__ out) {
    __shared__ float red[256];
    __shared__ int bounds[2];
    int g   = blockIdx.x;
    int tid = threadIdx.x;
    if (tid < 2) {
        int target = g + tid;   // lower_bound(batch, target)
        int lo = 0, hi = N_NODES;
        while (lo < hi) {
            int mid = (lo + hi) >> 1;
            if (batch[mid] < target) lo = mid + 1; else hi = mid;
        }
        bounds[tid] = lo;
    }
    __syncthreads();
    int start = bounds[0], end = bounds[1];
    int f = tid & 15, r = tid >> 4;
    float acc = 0.f;
    for (int v = start + r; v < end; v += 16)
        acc += __half2float(h[v * HIDDEN + f]);
    red[tid] = acc;
    __syncthreads();
    for (int off = 128; off >= 16; off >>= 1) {
        if (tid < off) red[tid] += red[tid + off];
        __syncthreads();
    }
    if (tid < N_CLASSES) {
        float s = blin[tid];
#pragma unroll
        for (int fe = 0; fe < HIDDEN; ++fe) s += red[fe] * Wlin[fe * N_CLASSES + tid];
        out[g * N_CLASSES + tid] = s;
    }
}

// ---------------- launch ----------------

extern "C" void kernel_launch(void* const* d_in, const int* in_sizes, int n_in,
                              void* d_out, int out_size, void* d_ws, size_t ws_size,
                              hipStream_t stream) {
    const float* x     = (const float*)d_in[0];
    const int*   ei    = (const int*)d_in[1];
    const int*   src   = ei;
    const int*   dst   = ei + N_EDGES;
    const int*   batch = (const int*)d_in[2];
    const float* W1 = (const float*)d_in[3];
    const float* b1 = (const float*)d_in[4];
    const float* W2 = (const float*)d_in[5];
    const float* b2 = (const float*)d_in[6];
    const float* W3 = (const float*)d_in[7];
    const float* b3 = (const float*)d_in[8];
    const float* Wlin = (const float*)d_in[9];
    const float* blin = (const float*)d_in[10];
    float* out = (float*)d_out;

    char* w = (char*)d_ws;
    auto alloc = [&](size_t bytes) -> char* {
        char* p = w;
        w += (bytes + 255) & ~(size_t)255;
        return p;
    };
    int*    cur    = (int*)alloc((size_t)NBUCKET * 4);
    int*    rp_beg = (int*)alloc((size_t)N_NODES * 4);
    int*    rp_end = (int*)alloc((size_t)N_NODES * 4);
    float*  dinv   = (float*)alloc((size_t)N_NODES * 4);
    __half* g      = (__half*)alloc((size_t)N_NODES * HIDDEN * 2);
    __half* hA     = (__half*)alloc((size_t)N_NODES * HIDDEN * 2);
    __half* hB     = (__half*)alloc((size_t)N_NODES * HIDDEN * 2);
    unsigned* part = (unsigned*)alloc((size_t)NBUCKET * PSLACK * 4);  // 24.8 MB
    int*    csr    = (int*)alloc((size_t)NBUCKET * CSLACK * 4 + 64);  // 16.0 MB

    int nbn = (N_NODES + 255) / 256;        // 391
    int ab  = (N_NODES + 15) / 16;          // 6250

    cursor_init_kernel<<<(NBUCKET + 255) / 256, 256, 0, stream>>>(cur);
    partition_kernel<<<PBLK, 512, 0, stream>>>(src, dst, cur, part);
    build_csr_kernel<<<NBUCKET, 512, 0, stream>>>(part, cur, rp_beg, rp_end, dinv, csr);

    // layer 1
    transform_x_kernel<<<nbn, 256, 0, stream>>>(x, W1, dinv, g);
    aggregate_kernel<<<ab, 256, 0, stream>>>(g, rp_beg, rp_end, csr, dinv, b1, hA, 1);
    // layer 2
    transform_h_kernel<<<nbn, 256, 0, stream>>>(hA, W2, dinv, g);
    aggregate_kernel<<<ab, 256, 0, stream>>>(g, rp_beg, rp_end, csr, dinv, b2, hB, 1);
    // layer 3 (no relu)
    transform_h_kernel<<<nbn, 256, 0, stream>>>(hB, W3, dinv, g);
    aggregate_kernel<<<ab, 256, 0, stream>>>(g, rp_beg, rp_end, csr, dinv, b3, hA, 0);

    pool_head_kernel<<<N_GRAPHS, 256, 0, stream>>>(hA, batch, Wlin, blin, out);
}